// Round 12
// baseline (352.313 us; speedup 1.0000x reference)
//
#include <hip/hip_runtime.h>
#include <math.h>

#define N_NODES 50000
#define N_PAD   50048
#define N_EDGES 800000
#define FEAT 128
#define K2 256
#define N_GRAPHS 512
#define N_CLASSES 10
#define BCAP 64          // bucket capacity (deg ~ Poisson(16); P(>64) ~ 0)
#define RANGE_SZ 12500   // 50000 / 4 dst ranges

typedef __attribute__((ext_vector_type(8))) short short8;
typedef __attribute__((ext_vector_type(4))) float floatx4;

// ---------- bf16 helpers ----------
__device__ __forceinline__ float bflo(unsigned u) { return __uint_as_float(u << 16); }
__device__ __forceinline__ float bfhi(unsigned u) { return __uint_as_float(u & 0xffff0000u); }
__device__ __forceinline__ unsigned short f2bf(float f) {
    unsigned u = __float_as_uint(f);
    u = (u + 0x7fffu + ((u >> 16) & 1u)) >> 16;   // RNE
    return (unsigned short)u;
}
__device__ __forceinline__ unsigned pack2(float a, float b) {
    return (unsigned)f2bf(a) | ((unsigned)f2bf(b) << 16);
}
// monotone float->uint key; encoded 0 is below every real value's key
__device__ __forceinline__ unsigned fkey(float f) {
    unsigned b = __float_as_uint(f);
    return (b & 0x80000000u) ? ~b : (b | 0x80000000u);
}
__device__ __forceinline__ float fdecode(unsigned k) {
    unsigned b = (k & 0x80000000u) ? (k ^ 0x80000000u) : ~k;
    return __uint_as_float(b);
}

// ---------- bucket fill: one edge per thread, dst-range partitioned ----------
__global__ __launch_bounds__(256) void fill_bucket(
    const int* __restrict__ src, const int* __restrict__ dst,
    int* __restrict__ cnt, unsigned short* __restrict__ bucket) {
    int range = blockIdx.x & 3;
    int chunk = blockIdx.x >> 2;            // 0..3124
    int e = chunk * 256 + threadIdx.x;      // one edge per thread
    int lo = range * RANGE_SZ;
    int d = dst[e];
    if (d >= lo && d < lo + RANGE_SZ) {
        int p = atomicAdd(&cnt[d], 1);
        if (p < BCAP) bucket[(size_t)d * BCAP + p] = (unsigned short)src[e];
    }
}

// ---------- setup: x -> bf16 into h-half of interleaved A | weights | goffs ----------
__global__ __launch_bounds__(256) void setup_kernel(
    const float* __restrict__ x, unsigned short* __restrict__ A,
    const float* __restrict__ wl1, const float* __restrict__ wr1,
    const float* __restrict__ wl23, const float* __restrict__ wr23,
    unsigned short* __restrict__ wt,
    const int* __restrict__ batch, int* __restrict__ goffs) {
    int b = blockIdx.x;
    if (b < 6250) {
        int idx = b * 256 + threadIdx.x;   // n*32 + f4
        if (idx < N_NODES * 32) {
            int n = idx >> 5, f4 = idx & 31;
            float4 v = ((const float4*)(x + (size_t)n * FEAT))[f4];
            uint2 o = make_uint2(pack2(v.x, v.y), pack2(v.z, v.w));
            *(uint2*)(A + (size_t)n * K2 + FEAT + f4 * 4) = o;
        }
    } else if (b < 6250 + 384) {
        int idx = (b - 6250) * 256 + threadIdx.x;  // 0..98303
        int layer = idx >> 15;
        int r = idx & 32767;
        int n = r >> 8, k = r & 255;
        const float* wl = (layer == 0) ? wl1 : wl23 + (size_t)(layer - 1) * FEAT * FEAT;
        const float* wr = (layer == 0) ? wr1 : wr23 + (size_t)(layer - 1) * FEAT * FEAT;
        float v = (k < FEAT) ? wl[k * FEAT + n] : wr[(k - FEAT) * FEAT + n];
        wt[idx] = f2bf(v);
    } else {
        int g = (b - 6250 - 384) * 256 + threadIdx.x;
        if (g > N_GRAPHS) return;
        int lo = 0, hi = N_NODES;
        while (lo < hi) {
            int mid = (lo + hi) >> 1;
            if (batch[mid] < g) lo = mid + 1; else hi = mid;
        }
        goffs[g] = lo;
    }
}

// ---------- aggregation: wave = node; 16-lane groups, dwordx4 gathers ----------
// hin = A + FEAT (h-half, row stride K2); writes agg-half at A base.
__device__ __forceinline__ void acc8(float* acc, uint4 u) {
    acc[0] += bflo(u.x); acc[1] += bfhi(u.x);
    acc[2] += bflo(u.y); acc[3] += bfhi(u.y);
    acc[4] += bflo(u.z); acc[5] += bfhi(u.z);
    acc[6] += bflo(u.w); acc[7] += bfhi(u.w);
}

__global__ __launch_bounds__(256) void aggregate_bf16(
    const unsigned short* __restrict__ hin, const int* __restrict__ cnt,
    const unsigned short* __restrict__ bucket, unsigned short* __restrict__ aggout) {
    int n = blockIdx.x * 4 + (threadIdx.x >> 6);
    if (n >= N_NODES) return;
    int lane = threadIdx.x & 63;
    int g = lane >> 4;        // edge slot within quad
    int l16 = lane & 15;      // 16 lanes x 16 B = 256 B row
    int deg = cnt[n];
    int c = min(deg, BCAP);
    int nq = c >> 2;
    int rem = c & 3;
    const unsigned short* cp = bucket + (size_t)n * BCAP;

    float acc[8];
    #pragma unroll
    for (int i = 0; i < 8; ++i) acc[i] = 0.f;

    int i = 0;
    for (; i + 4 <= nq; i += 4) {
        int s0 = cp[i * 4 + g];
        int s1 = cp[i * 4 + 4 + g];
        int s2 = cp[i * 4 + 8 + g];
        int s3 = cp[i * 4 + 12 + g];
        uint4 u0 = *(const uint4*)(hin + (size_t)s0 * K2 + l16 * 8);
        uint4 u1 = *(const uint4*)(hin + (size_t)s1 * K2 + l16 * 8);
        uint4 u2 = *(const uint4*)(hin + (size_t)s2 * K2 + l16 * 8);
        uint4 u3 = *(const uint4*)(hin + (size_t)s3 * K2 + l16 * 8);
        acc8(acc, u0); acc8(acc, u1); acc8(acc, u2); acc8(acc, u3);
    }
    if (i + 2 <= nq) {
        int s0 = cp[i * 4 + g];
        int s1 = cp[i * 4 + 4 + g];
        uint4 u0 = *(const uint4*)(hin + (size_t)s0 * K2 + l16 * 8);
        uint4 u1 = *(const uint4*)(hin + (size_t)s1 * K2 + l16 * 8);
        acc8(acc, u0); acc8(acc, u1);
        i += 2;
    }
    if (i < nq) {
        int s0 = cp[i * 4 + g];
        uint4 u0 = *(const uint4*)(hin + (size_t)s0 * K2 + l16 * 8);
        acc8(acc, u0);
    }
    if (g < rem) {
        int s0 = cp[nq * 4 + g];
        uint4 u0 = *(const uint4*)(hin + (size_t)s0 * K2 + l16 * 8);
        acc8(acc, u0);
    }
    #pragma unroll
    for (int j = 0; j < 8; ++j) {
        acc[j] += __shfl_xor(acc[j], 16);
        acc[j] += __shfl_xor(acc[j], 32);
    }
    if (g == 0) {
        float inv = 1.0f / fmaxf((float)deg, 1.0f);
        uint4 o;
        o.x = pack2(acc[0] * inv, acc[1] * inv);
        o.y = pack2(acc[2] * inv, acc[3] * inv);
        o.z = pack2(acc[4] * inv, acc[5] * inv);
        o.w = pack2(acc[6] * inv, acc[7] * inv);
        *(uint4*)(aggout + (size_t)n * K2 + l16 * 8) = o;
    }
}

// ---------- MFMA GEMM (R5 shape): h-half = relu(Arow @ Wt^T + b), in place ----------
// A rows are [agg(128)|h(128)] bf16 = 512 B contiguous; 128 rows/block,
// 32 rows/wave (2 bands). B streamed from global (64 KB, L2-hot). Each block
// reads only its own rows; stores depend on acc -> on all own-row loads, so
// the in-place h-half update cannot race. Layer 3 fuses the gate epilogue
// (gate_b cancels in the segment softmax).
__global__ __launch_bounds__(256) void gemm_mfma(
    unsigned short* __restrict__ A, const unsigned short* __restrict__ Wt,
    const float* __restrict__ bias,
    const float* __restrict__ gate_w, float* __restrict__ gate,
    unsigned* __restrict__ gmax, const int* __restrict__ batch) {
    int wave = threadIdx.x >> 6, lane = threadIdx.x & 63;
    int q = lane >> 4, l16 = lane & 15;
    int row0 = blockIdx.x * 128 + wave * 32;
    const unsigned short* pa0 = A + (size_t)(row0 + l16) * K2 + q * 8;
    const unsigned short* pa1 = pa0 + 16 * K2;
    const unsigned short* pb  = Wt + (size_t)l16 * K2 + q * 8;

    floatx4 acc[2][8];
    #pragma unroll
    for (int i = 0; i < 2; ++i)
        #pragma unroll
        for (int j = 0; j < 8; ++j) acc[i][j] = (floatx4){0.f, 0.f, 0.f, 0.f};

    #pragma unroll
    for (int ks = 0; ks < 8; ++ks) {
        short8 a0 = *(const short8*)(pa0 + ks * 32);
        short8 a1 = *(const short8*)(pa1 + ks * 32);
        #pragma unroll
        for (int nb = 0; nb < 8; ++nb) {
            short8 b = *(const short8*)(pb + (size_t)nb * 16 * K2 + ks * 32);
            acc[0][nb] = __builtin_amdgcn_mfma_f32_16x16x32_bf16(a0, b, acc[0][nb], 0, 0, 0);
            acc[1][nb] = __builtin_amdgcn_mfma_f32_16x16x32_bf16(a1, b, acc[1][nb], 0, 0, 0);
        }
    }

    float bv[8], gwv[8];
    #pragma unroll
    for (int nb = 0; nb < 8; ++nb) bv[nb] = bias[nb * 16 + l16];
    if (gate_w) {
        #pragma unroll
        for (int nb = 0; nb < 8; ++nb) gwv[nb] = gate_w[nb * 16 + l16];
    }

    #pragma unroll
    for (int band = 0; band < 2; ++band) {
        #pragma unroll
        for (int r = 0; r < 4; ++r) {
            int m = row0 + band * 16 + q * 4 + r;
            float gsum = 0.f;
            #pragma unroll
            for (int nb = 0; nb < 8; ++nb) {
                float v = fmaxf(acc[band][nb][r] + bv[nb], 0.f);
                if (m < N_NODES) A[(size_t)m * K2 + FEAT + nb * 16 + l16] = f2bf(v);
                if (gate_w) gsum += v * gwv[nb];
            }
            if (gate_w) {
                gsum += __shfl_xor(gsum, 1);
                gsum += __shfl_xor(gsum, 2);
                gsum += __shfl_xor(gsum, 4);
                gsum += __shfl_xor(gsum, 8);
                if (l16 == 0 && m < N_NODES) {
                    gate[m] = gsum;
                    atomicMax(&gmax[batch[m]], fkey(gsum));
                }
            }
        }
    }
}

// ---------- pooling + head: one block (256 thr) per graph, single h pass ----------
// h = A + FEAT (row stride K2)
__global__ __launch_bounds__(256) void pool_head(
    const unsigned short* __restrict__ h, const float* __restrict__ gate,
    const unsigned* __restrict__ gmax, const int* __restrict__ goffs,
    const float* __restrict__ w1, const float* __restrict__ b1,
    const float* __restrict__ w2, const float* __restrict__ b2,
    float* __restrict__ out) {
    __shared__ float sred[4];
    __shared__ float facc[4][128];
    __shared__ float pv[128], qv[128], lg[N_CLASSES];
    int g = blockIdx.x;
    int s = goffs[g], e = goffs[g + 1];
    int t = threadIdx.x;
    int wave = t >> 6, lane = t & 63;

    if (s < e) {
        float m = fdecode(gmax[g]);
        float d = 0.f;
        for (int n = s + t; n < e; n += 256) d += __expf(gate[n] - m);
        #pragma unroll
        for (int off = 32; off; off >>= 1) d += __shfl_xor(d, off);
        if (lane == 0) sred[wave] = d;
        __syncthreads();
        float den = sred[0] + sred[1] + sred[2] + sred[3];
        float acc0 = 0.f, acc1 = 0.f;
        for (int n = s + wave; n < e; n += 4) {
            float gn = __expf(gate[n] - m);
            unsigned u = *(const unsigned*)(h + (size_t)n * K2 + lane * 2);
            acc0 += gn * bflo(u);
            acc1 += gn * bfhi(u);
        }
        facc[wave][lane * 2]     = acc0;
        facc[wave][lane * 2 + 1] = acc1;
        __syncthreads();
        if (t < 128) pv[t] = (facc[0][t] + facc[1][t] + facc[2][t] + facc[3][t]) / den;
    } else {
        if (t < 128) pv[t] = 0.f;
    }
    __syncthreads();

    if (t < 128) {
        float acc = b1[t];
        #pragma unroll 4
        for (int k = 0; k < 128; ++k) acc += pv[k] * w1[k * FEAT + t];
        qv[t] = fmaxf(acc, 0.f);
    }
    __syncthreads();
    if (t < N_CLASSES) {
        float a = b2[t];
        #pragma unroll 4
        for (int k = 0; k < 128; ++k) a += qv[k] * w2[k * N_CLASSES + t];
        lg[t] = a;
    }
    __syncthreads();
    if (t < N_CLASSES) {
        float m = -INFINITY;
        #pragma unroll
        for (int j = 0; j < N_CLASSES; ++j) m = fmaxf(m, lg[j]);
        float sum = 0.f;
        #pragma unroll
        for (int j = 0; j < N_CLASSES; ++j) sum += __expf(lg[j] - m);
        out[(size_t)g * N_CLASSES + t] = lg[t] - m - __logf(sum);
    }
}

// ---------- launch ----------
static inline size_t align256(size_t x) { return (x + 255) & ~(size_t)255; }

extern "C" void kernel_launch(void* const* d_in, const int* in_sizes, int n_in,
                              void* d_out, int out_size, void* d_ws, size_t ws_size,
                              hipStream_t stream) {
    const float* x        = (const float*)d_in[0];
    const int*   ei       = (const int*)d_in[1];
    const int*   batch    = (const int*)d_in[2];
    const float* conv1_wl = (const float*)d_in[4];
    const float* conv1_wr = (const float*)d_in[5];
    const float* conv1_b  = (const float*)d_in[6];
    const float* convs_wl = (const float*)d_in[7];
    const float* convs_wr = (const float*)d_in[8];
    const float* convs_b  = (const float*)d_in[9];
    const float* gate_w   = (const float*)d_in[10];
    const float* lin1_w   = (const float*)d_in[12];
    const float* lin1_b   = (const float*)d_in[13];
    const float* lin2_w   = (const float*)d_in[14];
    const float* lin2_b   = (const float*)d_in[15];
    float* out = (float*)d_out;

    const int* src = ei;
    const int* dst = ei + N_EDGES;

    char* w = (char*)d_ws;
    size_t off = 0;
    unsigned short* A1   = (unsigned short*)(w + off); off += align256((size_t)N_PAD * K2 * 2);
    unsigned short* bkt  = (unsigned short*)(w + off); off += align256((size_t)N_NODES * BCAP * 2);
    unsigned short* wt   = (unsigned short*)(w + off); off += align256((size_t)3 * FEAT * K2 * 2);
    float* f_gate = (float*)(w + off); off += align256((size_t)N_NODES * 4);
    int*   i_goff = (int*)(w + off);   off += align256((size_t)(N_GRAPHS + 1) * 4);
    // zero region: cnt + gmax contiguous
    char* zbase = w + off;
    int*      i_cnt  = (int*)(w + off);      off += align256((size_t)N_NODES * 4);
    unsigned* u_gmax = (unsigned*)(w + off); off += align256((size_t)N_GRAPHS * 4);
    size_t zbytes = (size_t)((w + off) - zbase);

    hipMemsetAsync(zbase, 0, zbytes, stream);

    fill_bucket<<<12500, 256, 0, stream>>>(src, dst, i_cnt, bkt);
    setup_kernel<<<6250 + 384 + 3, 256, 0, stream>>>(
        x, A1, conv1_wl, conv1_wr, convs_wl, convs_wr, wt, batch, i_goff);

    const int AB = (N_NODES + 3) / 4;   // 12500
    const int GB = N_PAD / 128;         // 391

    aggregate_bf16<<<AB, 256, 0, stream>>>(A1 + FEAT, i_cnt, bkt, A1);
    gemm_mfma<<<GB, 256, 0, stream>>>(A1, wt, conv1_b,
                                      nullptr, nullptr, nullptr, nullptr);
    aggregate_bf16<<<AB, 256, 0, stream>>>(A1 + FEAT, i_cnt, bkt, A1);
    gemm_mfma<<<GB, 256, 0, stream>>>(A1, wt + FEAT * K2, convs_b,
                                      nullptr, nullptr, nullptr, nullptr);
    aggregate_bf16<<<AB, 256, 0, stream>>>(A1 + FEAT, i_cnt, bkt, A1);
    gemm_mfma<<<GB, 256, 0, stream>>>(A1, wt + 2 * FEAT * K2, convs_b + FEAT,
                                      gate_w, f_gate, u_gmax, batch);

    pool_head<<<N_GRAPHS, 256, 0, stream>>>(A1 + FEAT, f_gate, u_gmax, i_goff,
                                            lin1_w, lin1_b, lin2_w, lin2_b, out);
}

// Round 13
// 341.080 us; speedup vs baseline: 1.0329x; 1.0329x over previous
//
#include <hip/hip_runtime.h>
#include <math.h>

#define N_NODES 50000
#define N_PAD   50048
#define N_EDGES 800000
#define FEAT 128
#define K2 256
#define N_GRAPHS 512
#define N_CLASSES 10
#define BCAP 64          // bucket capacity (deg ~ Poisson(16); P(>64) ~ 0)
#define RANGE_SZ 12500   // 50000 / 4 dst ranges
#define WROW 264         // padded LDS row stride (shorts)
#define TILE_ROWS 64
#define GEMM_BLOCKS 256  // persistent: 1 block/CU, ~3 tiles each
#define N_TILES 782      // N_PAD / TILE_ROWS

typedef __attribute__((ext_vector_type(8))) short short8;
typedef __attribute__((ext_vector_type(4))) float floatx4;

// ---------- bf16 helpers ----------
__device__ __forceinline__ float bflo(unsigned u) { return __uint_as_float(u << 16); }
__device__ __forceinline__ float bfhi(unsigned u) { return __uint_as_float(u & 0xffff0000u); }
__device__ __forceinline__ unsigned short f2bf(float f) {
    unsigned u = __float_as_uint(f);
    u = (u + 0x7fffu + ((u >> 16) & 1u)) >> 16;   // RNE
    return (unsigned short)u;
}
__device__ __forceinline__ unsigned pack2(float a, float b) {
    return (unsigned)f2bf(a) | ((unsigned)f2bf(b) << 16);
}
// monotone float->uint key; encoded 0 is below every real value's key
__device__ __forceinline__ unsigned fkey(float f) {
    unsigned b = __float_as_uint(f);
    return (b & 0x80000000u) ? ~b : (b | 0x80000000u);
}
__device__ __forceinline__ float fdecode(unsigned k) {
    unsigned b = (k & 0x80000000u) ? (k ^ 0x80000000u) : ~k;
    return __uint_as_float(b);
}

// ---------- bucket fill: one edge per thread, dst-range partitioned ----------
__global__ __launch_bounds__(256) void fill_bucket(
    const int* __restrict__ src, const int* __restrict__ dst,
    int* __restrict__ cnt, unsigned short* __restrict__ bucket) {
    int range = blockIdx.x & 3;
    int chunk = blockIdx.x >> 2;            // 0..3124
    int e = chunk * 256 + threadIdx.x;      // one edge per thread
    int lo = range * RANGE_SZ;
    int d = dst[e];
    if (d >= lo && d < lo + RANGE_SZ) {
        int p = atomicAdd(&cnt[d], 1);
        if (p < BCAP) bucket[(size_t)d * BCAP + p] = (unsigned short)src[e];
    }
}

// ---------- setup: x -> bf16 into h-half of interleaved A | weights | goffs ----------
__global__ __launch_bounds__(256) void setup_kernel(
    const float* __restrict__ x, unsigned short* __restrict__ A,
    const float* __restrict__ wl1, const float* __restrict__ wr1,
    const float* __restrict__ wl23, const float* __restrict__ wr23,
    unsigned short* __restrict__ wt,
    const int* __restrict__ batch, int* __restrict__ goffs) {
    int b = blockIdx.x;
    if (b < 6250) {
        int idx = b * 256 + threadIdx.x;   // n*32 + f4
        if (idx < N_NODES * 32) {
            int n = idx >> 5, f4 = idx & 31;
            float4 v = ((const float4*)(x + (size_t)n * FEAT))[f4];
            uint2 o = make_uint2(pack2(v.x, v.y), pack2(v.z, v.w));
            *(uint2*)(A + (size_t)n * K2 + FEAT + f4 * 4) = o;
        }
    } else if (b < 6250 + 384) {
        int idx = (b - 6250) * 256 + threadIdx.x;  // 0..98303
        int layer = idx >> 15;
        int r = idx & 32767;
        int n = r >> 8, k = r & 255;
        const float* wl = (layer == 0) ? wl1 : wl23 + (size_t)(layer - 1) * FEAT * FEAT;
        const float* wr = (layer == 0) ? wr1 : wr23 + (size_t)(layer - 1) * FEAT * FEAT;
        float v = (k < FEAT) ? wl[k * FEAT + n] : wr[(k - FEAT) * FEAT + n];
        wt[idx] = f2bf(v);
    } else {
        int g = (b - 6250 - 384) * 256 + threadIdx.x;
        if (g > N_GRAPHS) return;
        int lo = 0, hi = N_NODES;
        while (lo < hi) {
            int mid = (lo + hi) >> 1;
            if (batch[mid] < g) lo = mid + 1; else hi = mid;
        }
        goffs[g] = lo;
    }
}

// ---------- aggregation: wave = node; 16-lane groups, dwordx4 gathers ----------
__device__ __forceinline__ void acc8(float* acc, uint4 u) {
    acc[0] += bflo(u.x); acc[1] += bfhi(u.x);
    acc[2] += bflo(u.y); acc[3] += bfhi(u.y);
    acc[4] += bflo(u.z); acc[5] += bfhi(u.z);
    acc[6] += bflo(u.w); acc[7] += bfhi(u.w);
}

__global__ __launch_bounds__(256) void aggregate_bf16(
    const unsigned short* __restrict__ hin, const int* __restrict__ cnt,
    const unsigned short* __restrict__ bucket, unsigned short* __restrict__ aggout) {
    int n = blockIdx.x * 4 + (threadIdx.x >> 6);
    if (n >= N_NODES) return;
    int lane = threadIdx.x & 63;
    int g = lane >> 4;        // edge slot within quad
    int l16 = lane & 15;      // 16 lanes x 16 B = 256 B row
    int deg = cnt[n];
    int c = min(deg, BCAP);
    int nq = c >> 2;
    int rem = c & 3;
    const unsigned short* cp = bucket + (size_t)n * BCAP;

    float acc[8];
    #pragma unroll
    for (int i = 0; i < 8; ++i) acc[i] = 0.f;

    int i = 0;
    for (; i + 4 <= nq; i += 4) {
        int s0 = cp[i * 4 + g];
        int s1 = cp[i * 4 + 4 + g];
        int s2 = cp[i * 4 + 8 + g];
        int s3 = cp[i * 4 + 12 + g];
        uint4 u0 = *(const uint4*)(hin + (size_t)s0 * K2 + l16 * 8);
        uint4 u1 = *(const uint4*)(hin + (size_t)s1 * K2 + l16 * 8);
        uint4 u2 = *(const uint4*)(hin + (size_t)s2 * K2 + l16 * 8);
        uint4 u3 = *(const uint4*)(hin + (size_t)s3 * K2 + l16 * 8);
        acc8(acc, u0); acc8(acc, u1); acc8(acc, u2); acc8(acc, u3);
    }
    if (i + 2 <= nq) {
        int s0 = cp[i * 4 + g];
        int s1 = cp[i * 4 + 4 + g];
        uint4 u0 = *(const uint4*)(hin + (size_t)s0 * K2 + l16 * 8);
        uint4 u1 = *(const uint4*)(hin + (size_t)s1 * K2 + l16 * 8);
        acc8(acc, u0); acc8(acc, u1);
        i += 2;
    }
    if (i < nq) {
        int s0 = cp[i * 4 + g];
        uint4 u0 = *(const uint4*)(hin + (size_t)s0 * K2 + l16 * 8);
        acc8(acc, u0);
    }
    if (g < rem) {
        int s0 = cp[nq * 4 + g];
        uint4 u0 = *(const uint4*)(hin + (size_t)s0 * K2 + l16 * 8);
        acc8(acc, u0);
    }
    #pragma unroll
    for (int j = 0; j < 8; ++j) {
        acc[j] += __shfl_xor(acc[j], 16);
        acc[j] += __shfl_xor(acc[j], 32);
    }
    if (g == 0) {
        float inv = 1.0f / fmaxf((float)deg, 1.0f);
        uint4 o;
        o.x = pack2(acc[0] * inv, acc[1] * inv);
        o.y = pack2(acc[2] * inv, acc[3] * inv);
        o.z = pack2(acc[4] * inv, acc[5] * inv);
        o.w = pack2(acc[6] * inv, acc[7] * inv);
        *(uint4*)(aggout + (size_t)n * K2 + l16 * 8) = o;
    }
}

// ---------- persistent MFMA GEMM: h-half = relu(Arow @ Wt^T + b), in place ----------
// 256 blocks (1/CU). Per block: stage Wt (64 KB) into LDS once, then
// grid-stride over 64-row tiles (16 rows/wave) with register-double-buffered
// A prefetch — next tile's 8 A-frags issue before the current tile's MFMA
// loop, hiding vmem latency under LDS+MFMA work. The cold-start latency is
// paid once per CU instead of once per 128-row block (the R9-R12 mistake).
// In-place safe: every block reads/writes only its own tiles' rows.
// Layer 3 fuses the gate epilogue (gate_b cancels in segment softmax).
__global__ __launch_bounds__(256) void gemm_mfma(
    unsigned short* __restrict__ A, const unsigned short* __restrict__ Wt,
    const float* __restrict__ bias,
    const float* __restrict__ gate_w, float* __restrict__ gate,
    unsigned* __restrict__ gmax, const int* __restrict__ batch) {
    __shared__ unsigned short sB[128 * WROW];
    int t = threadIdx.x;
    int wave = t >> 6, lane = t & 63;
    int q = lane >> 4, l16 = lane & 15;

    // stage Wt into padded LDS (coalesced 16 B frags)
    #pragma unroll
    for (int i = 0; i < 16; ++i) {
        int flat = i * 256 + t;            // frag id 0..4095
        int rw = flat >> 5, fr = flat & 31;
        uint4 v = *(const uint4*)(Wt + (size_t)flat * 8);
        *(uint4*)(&sB[rw * WROW + fr * 8]) = v;
    }

    float bv[8], gwv[8];
    #pragma unroll
    for (int nb = 0; nb < 8; ++nb) bv[nb] = bias[nb * 16 + l16];
    if (gate_w) {
        #pragma unroll
        for (int nb = 0; nb < 8; ++nb) gwv[nb] = gate_w[nb * 16 + l16];
    }

    int tile = blockIdx.x;
    short8 a[8];
    {   // prefetch first tile (overlaps LDS staging; barrier below waits both)
        const unsigned short* pa =
            A + (size_t)(tile * TILE_ROWS + wave * 16 + l16) * K2 + q * 8;
        #pragma unroll
        for (int ks = 0; ks < 8; ++ks) a[ks] = *(const short8*)(pa + ks * 32);
    }
    __syncthreads();

    while (tile < N_TILES) {
        int ntile = tile + GEMM_BLOCKS;
        short8 an[8];
        if (ntile < N_TILES) {
            const unsigned short* pa =
                A + (size_t)(ntile * TILE_ROWS + wave * 16 + l16) * K2 + q * 8;
            #pragma unroll
            for (int ks = 0; ks < 8; ++ks) an[ks] = *(const short8*)(pa + ks * 32);
        }

        floatx4 acc[8];
        #pragma unroll
        for (int j = 0; j < 8; ++j) acc[j] = (floatx4){0.f, 0.f, 0.f, 0.f};

        #pragma unroll
        for (int ks = 0; ks < 8; ++ks) {
            #pragma unroll
            for (int nb = 0; nb < 8; ++nb) {
                short8 b = *(const short8*)(&sB[(nb * 16 + l16) * WROW + ks * 32 + q * 8]);
                acc[nb] = __builtin_amdgcn_mfma_f32_16x16x32_bf16(a[ks], b, acc[nb], 0, 0, 0);
            }
        }

        int row0 = tile * TILE_ROWS + wave * 16;
        #pragma unroll
        for (int r = 0; r < 4; ++r) {
            int m = row0 + q * 4 + r;
            float gsum = 0.f;
            #pragma unroll
            for (int nb = 0; nb < 8; ++nb) {
                float v = fmaxf(acc[nb][r] + bv[nb], 0.f);
                if (m < N_NODES) A[(size_t)m * K2 + FEAT + nb * 16 + l16] = f2bf(v);
                if (gate_w) gsum += v * gwv[nb];
            }
            if (gate_w) {
                gsum += __shfl_xor(gsum, 1);
                gsum += __shfl_xor(gsum, 2);
                gsum += __shfl_xor(gsum, 4);
                gsum += __shfl_xor(gsum, 8);
                if (l16 == 0 && m < N_NODES) {
                    gate[m] = gsum;
                    atomicMax(&gmax[batch[m]], fkey(gsum));
                }
            }
        }
        tile = ntile;
        #pragma unroll
        for (int ks = 0; ks < 8; ++ks) a[ks] = an[ks];
    }
}

// ---------- pooling + head: one block (256 thr) per graph, single h pass ----------
// h = A + FEAT (row stride K2)
__global__ __launch_bounds__(256) void pool_head(
    const unsigned short* __restrict__ h, const float* __restrict__ gate,
    const unsigned* __restrict__ gmax, const int* __restrict__ goffs,
    const float* __restrict__ w1, const float* __restrict__ b1,
    const float* __restrict__ w2, const float* __restrict__ b2,
    float* __restrict__ out) {
    __shared__ float sred[4];
    __shared__ float facc[4][128];
    __shared__ float pv[128], qv[128], lg[N_CLASSES];
    int g = blockIdx.x;
    int s = goffs[g], e = goffs[g + 1];
    int t = threadIdx.x;
    int wave = t >> 6, lane = t & 63;

    if (s < e) {
        float m = fdecode(gmax[g]);
        float d = 0.f;
        for (int n = s + t; n < e; n += 256) d += __expf(gate[n] - m);
        #pragma unroll
        for (int off = 32; off; off >>= 1) d += __shfl_xor(d, off);
        if (lane == 0) sred[wave] = d;
        __syncthreads();
        float den = sred[0] + sred[1] + sred[2] + sred[3];
        float acc0 = 0.f, acc1 = 0.f;
        for (int n = s + wave; n < e; n += 4) {
            float gn = __expf(gate[n] - m);
            unsigned u = *(const unsigned*)(h + (size_t)n * K2 + lane * 2);
            acc0 += gn * bflo(u);
            acc1 += gn * bfhi(u);
        }
        facc[wave][lane * 2]     = acc0;
        facc[wave][lane * 2 + 1] = acc1;
        __syncthreads();
        if (t < 128) pv[t] = (facc[0][t] + facc[1][t] + facc[2][t] + facc[3][t]) / den;
    } else {
        if (t < 128) pv[t] = 0.f;
    }
    __syncthreads();

    if (t < 128) {
        float acc = b1[t];
        #pragma unroll 4
        for (int k = 0; k < 128; ++k) acc += pv[k] * w1[k * FEAT + t];
        qv[t] = fmaxf(acc, 0.f);
    }
    __syncthreads();
    if (t < N_CLASSES) {
        float a = b2[t];
        #pragma unroll 4
        for (int k = 0; k < 128; ++k) a += qv[k] * w2[k * N_CLASSES + t];
        lg[t] = a;
    }
    __syncthreads();
    if (t < N_CLASSES) {
        float m = -INFINITY;
        #pragma unroll
        for (int j = 0; j < N_CLASSES; ++j) m = fmaxf(m, lg[j]);
        float sum = 0.f;
        #pragma unroll
        for (int j = 0; j < N_CLASSES; ++j) sum += __expf(lg[j] - m);
        out[(size_t)g * N_CLASSES + t] = lg[t] - m - __logf(sum);
    }
}

// ---------- launch ----------
static inline size_t align256(size_t x) { return (x + 255) & ~(size_t)255; }

extern "C" void kernel_launch(void* const* d_in, const int* in_sizes, int n_in,
                              void* d_out, int out_size, void* d_ws, size_t ws_size,
                              hipStream_t stream) {
    const float* x        = (const float*)d_in[0];
    const int*   ei       = (const int*)d_in[1];
    const int*   batch    = (const int*)d_in[2];
    const float* conv1_wl = (const float*)d_in[4];
    const float* conv1_wr = (const float*)d_in[5];
    const float* conv1_b  = (const float*)d_in[6];
    const float* convs_wl = (const float*)d_in[7];
    const float* convs_wr = (const float*)d_in[8];
    const float* convs_b  = (const float*)d_in[9];
    const float* gate_w   = (const float*)d_in[10];
    const float* lin1_w   = (const float*)d_in[12];
    const float* lin1_b   = (const float*)d_in[13];
    const float* lin2_w   = (const float*)d_in[14];
    const float* lin2_b   = (const float*)d_in[15];
    float* out = (float*)d_out;

    const int* src = ei;
    const int* dst = ei + N_EDGES;

    char* w = (char*)d_ws;
    size_t off = 0;
    unsigned short* A1   = (unsigned short*)(w + off); off += align256((size_t)N_PAD * K2 * 2);
    unsigned short* bkt  = (unsigned short*)(w + off); off += align256((size_t)N_NODES * BCAP * 2);
    unsigned short* wt   = (unsigned short*)(w + off); off += align256((size_t)3 * FEAT * K2 * 2);
    float* f_gate = (float*)(w + off); off += align256((size_t)N_NODES * 4);
    int*   i_goff = (int*)(w + off);   off += align256((size_t)(N_GRAPHS + 1) * 4);
    // zero region: cnt + gmax contiguous
    char* zbase = w + off;
    int*      i_cnt  = (int*)(w + off);      off += align256((size_t)N_NODES * 4);
    unsigned* u_gmax = (unsigned*)(w + off); off += align256((size_t)N_GRAPHS * 4);
    size_t zbytes = (size_t)((w + off) - zbase);

    hipMemsetAsync(zbase, 0, zbytes, stream);

    fill_bucket<<<12500, 256, 0, stream>>>(src, dst, i_cnt, bkt);
    setup_kernel<<<6250 + 384 + 3, 256, 0, stream>>>(
        x, A1, conv1_wl, conv1_wr, convs_wl, convs_wr, wt, batch, i_goff);

    const int AB = (N_NODES + 3) / 4;   // 12500

    aggregate_bf16<<<AB, 256, 0, stream>>>(A1 + FEAT, i_cnt, bkt, A1);
    gemm_mfma<<<GEMM_BLOCKS, 256, 0, stream>>>(A1, wt, conv1_b,
                                               nullptr, nullptr, nullptr, nullptr);
    aggregate_bf16<<<AB, 256, 0, stream>>>(A1 + FEAT, i_cnt, bkt, A1);
    gemm_mfma<<<GEMM_BLOCKS, 256, 0, stream>>>(A1, wt + FEAT * K2, convs_b,
                                               nullptr, nullptr, nullptr, nullptr);
    aggregate_bf16<<<AB, 256, 0, stream>>>(A1 + FEAT, i_cnt, bkt, A1);
    gemm_mfma<<<GEMM_BLOCKS, 256, 0, stream>>>(A1, wt + 2 * FEAT * K2, convs_b + FEAT,
                                               gate_w, f_gate, u_gmax, batch);

    pool_head<<<N_GRAPHS, 256, 0, stream>>>(A1 + FEAT, f_gate, u_gmax, i_goff,
                                            lin1_w, lin1_b, lin2_w, lin2_b, out);
}

// Round 14
// 300.093 us; speedup vs baseline: 1.1740x; 1.1366x over previous
//
#include <hip/hip_runtime.h>
#include <math.h>

#define N_NODES 50000
#define N_PAD   50048
#define N_EDGES 800000
#define FEAT 128
#define K2 256
#define N_GRAPHS 512
#define N_CLASSES 10
#define BCAP 64          // bucket capacity (deg ~ Poisson(16); P(>64) ~ 0)
#define RANGE_SZ 12500   // 50000 / 4 dst ranges
#define BROW 264         // sB row stride (shorts), pad for bank spread
#define OROW 72          // sOut row stride (shorts), 16B-aligned + bank spread

typedef __attribute__((ext_vector_type(8))) short short8;
typedef __attribute__((ext_vector_type(4))) float floatx4;

// ---------- bf16 helpers ----------
__device__ __forceinline__ float bflo(unsigned u) { return __uint_as_float(u << 16); }
__device__ __forceinline__ float bfhi(unsigned u) { return __uint_as_float(u & 0xffff0000u); }
__device__ __forceinline__ unsigned short f2bf(float f) {
    unsigned u = __float_as_uint(f);
    u = (u + 0x7fffu + ((u >> 16) & 1u)) >> 16;   // RNE
    return (unsigned short)u;
}
__device__ __forceinline__ unsigned pack2(float a, float b) {
    return (unsigned)f2bf(a) | ((unsigned)f2bf(b) << 16);
}

// ---------- bucket fill: one edge per thread, dst-range partitioned ----------
__global__ __launch_bounds__(256) void fill_bucket(
    const int* __restrict__ src, const int* __restrict__ dst,
    int* __restrict__ cnt, unsigned short* __restrict__ bucket) {
    int range = blockIdx.x & 3;
    int chunk = blockIdx.x >> 2;            // 0..3124
    int e = chunk * 256 + threadIdx.x;      // one edge per thread
    int lo = range * RANGE_SZ;
    int d = dst[e];
    if (d >= lo && d < lo + RANGE_SZ) {
        int p = atomicAdd(&cnt[d], 1);
        if (p < BCAP) bucket[(size_t)d * BCAP + p] = (unsigned short)src[e];
    }
}

// ---------- setup: x -> bf16 into h-half of interleaved A0 | weights | goffs ----------
__global__ __launch_bounds__(256) void setup_kernel(
    const float* __restrict__ x, unsigned short* __restrict__ A,
    const float* __restrict__ wl1, const float* __restrict__ wr1,
    const float* __restrict__ wl23, const float* __restrict__ wr23,
    unsigned short* __restrict__ wt,
    const int* __restrict__ batch, int* __restrict__ goffs) {
    int b = blockIdx.x;
    if (b < 6250) {
        int idx = b * 256 + threadIdx.x;   // n*32 + f4
        if (idx < N_NODES * 32) {
            int n = idx >> 5, f4 = idx & 31;
            float4 v = ((const float4*)(x + (size_t)n * FEAT))[f4];
            uint2 o = make_uint2(pack2(v.x, v.y), pack2(v.z, v.w));
            *(uint2*)(A + (size_t)n * K2 + FEAT + f4 * 4) = o;
        }
    } else if (b < 6250 + 384) {
        int idx = (b - 6250) * 256 + threadIdx.x;  // 0..98303
        int layer = idx >> 15;
        int r = idx & 32767;
        int n = r >> 8, k = r & 255;
        const float* wl = (layer == 0) ? wl1 : wl23 + (size_t)(layer - 1) * FEAT * FEAT;
        const float* wr = (layer == 0) ? wr1 : wr23 + (size_t)(layer - 1) * FEAT * FEAT;
        float v = (k < FEAT) ? wl[k * FEAT + n] : wr[(k - FEAT) * FEAT + n];
        wt[idx] = f2bf(v);
    } else {
        int g = (b - 6250 - 384) * 256 + threadIdx.x;
        if (g > N_GRAPHS) return;
        int lo = 0, hi = N_NODES;
        while (lo < hi) {
            int mid = (lo + hi) >> 1;
            if (batch[mid] < g) lo = mid + 1; else hi = mid;
        }
        goffs[g] = lo;
    }
}

// ---------- aggregation: wave = node; 16-lane groups, dwordx4 gathers ----------
// Reads X.h (stride K2 at +FEAT), writes X.agg (same row, other half): no hazard.
__device__ __forceinline__ void acc8(float* acc, uint4 u) {
    acc[0] += bflo(u.x); acc[1] += bfhi(u.x);
    acc[2] += bflo(u.y); acc[3] += bfhi(u.y);
    acc[4] += bflo(u.z); acc[5] += bfhi(u.z);
    acc[6] += bflo(u.w); acc[7] += bfhi(u.w);
}

__global__ __launch_bounds__(256) void aggregate_bf16(
    const unsigned short* __restrict__ hin, const int* __restrict__ cnt,
    const unsigned short* __restrict__ bucket, unsigned short* __restrict__ aggout) {
    int n = blockIdx.x * 4 + (threadIdx.x >> 6);
    if (n >= N_NODES) return;
    int lane = threadIdx.x & 63;
    int g = lane >> 4;        // edge slot within quad
    int l16 = lane & 15;      // 16 lanes x 16 B = 256 B row
    int deg = cnt[n];
    int c = min(deg, BCAP);
    int nq = c >> 2;
    int rem = c & 3;
    const unsigned short* cp = bucket + (size_t)n * BCAP;

    float acc[8];
    #pragma unroll
    for (int i = 0; i < 8; ++i) acc[i] = 0.f;

    int i = 0;
    for (; i + 4 <= nq; i += 4) {
        int s0 = cp[i * 4 + g];
        int s1 = cp[i * 4 + 4 + g];
        int s2 = cp[i * 4 + 8 + g];
        int s3 = cp[i * 4 + 12 + g];
        uint4 u0 = *(const uint4*)(hin + (size_t)s0 * K2 + l16 * 8);
        uint4 u1 = *(const uint4*)(hin + (size_t)s1 * K2 + l16 * 8);
        uint4 u2 = *(const uint4*)(hin + (size_t)s2 * K2 + l16 * 8);
        uint4 u3 = *(const uint4*)(hin + (size_t)s3 * K2 + l16 * 8);
        acc8(acc, u0); acc8(acc, u1); acc8(acc, u2); acc8(acc, u3);
    }
    if (i + 2 <= nq) {
        int s0 = cp[i * 4 + g];
        int s1 = cp[i * 4 + 4 + g];
        uint4 u0 = *(const uint4*)(hin + (size_t)s0 * K2 + l16 * 8);
        uint4 u1 = *(const uint4*)(hin + (size_t)s1 * K2 + l16 * 8);
        acc8(acc, u0); acc8(acc, u1);
        i += 2;
    }
    if (i < nq) {
        int s0 = cp[i * 4 + g];
        uint4 u0 = *(const uint4*)(hin + (size_t)s0 * K2 + l16 * 8);
        acc8(acc, u0);
    }
    if (g < rem) {
        int s0 = cp[nq * 4 + g];
        uint4 u0 = *(const uint4*)(hin + (size_t)s0 * K2 + l16 * 8);
        acc8(acc, u0);
    }
    #pragma unroll
    for (int j = 0; j < 8; ++j) {
        acc[j] += __shfl_xor(acc[j], 16);
        acc[j] += __shfl_xor(acc[j], 32);
    }
    if (g == 0) {
        float inv = 1.0f / fmaxf((float)deg, 1.0f);
        uint4 o;
        o.x = pack2(acc[0] * inv, acc[1] * inv);
        o.y = pack2(acc[2] * inv, acc[3] * inv);
        o.z = pack2(acc[4] * inv, acc[5] * inv);
        o.w = pack2(acc[6] * inv, acc[7] * inv);
        *(uint4*)(aggout + (size_t)n * K2 + l16 * 8) = o;
    }
}

// ---------- MFMA GEMM v6: Aout.h = relu(Ain.row @ Wt^T + b) ----------
// blockIdx = tileM*2 + nh: 128-row M-tile x 64-col N-half. Per wave: 32 rows
// (2 bands) x 64 cols, acc = 32 VGPRs. B-half (64x256) staged in LDS once;
// A-frags preloaded in ONE 16-load batch (single exposed vmem wait); MFMA
// loop reads B from LDS (lgkm counter). Output goes through a per-wave LDS
// transpose -> 4 coalesced dwordx4 stores/lane (full 64 B lines) instead of
// 64 scattered 2-byte stores. Pure out-of-place (ping-pong buffers).
// Layer 3: partial gate dot per n-half via 16-lane reduce + atomicAdd.
__global__ __launch_bounds__(256) void gemm_mfma(
    const unsigned short* __restrict__ Ain, unsigned short* __restrict__ Aout,
    const unsigned short* __restrict__ Wt, const float* __restrict__ bias,
    const float* __restrict__ gate_w, float* __restrict__ gate) {
    __shared__ unsigned short sB[64 * BROW];
    __shared__ unsigned short sOut[4][32 * OROW];
    int t = threadIdx.x;
    int wave = t >> 6, lane = t & 63;
    int q = lane >> 4, l16 = lane & 15;
    int tileM = blockIdx.x >> 1;
    int nh = blockIdx.x & 1;
    int row0 = tileM * 128 + wave * 32;

    // preload A fragments: one 16-load batch (rows row0..row0+31, full K=256)
    const unsigned short* pa0 = Ain + (size_t)(row0 + l16) * K2 + q * 8;
    const unsigned short* pa1 = pa0 + 16 * K2;
    short8 a0[8], a1[8];
    #pragma unroll
    for (int ks = 0; ks < 8; ++ks) {
        a0[ks] = *(const short8*)(pa0 + ks * 32);
        a1[ks] = *(const short8*)(pa1 + ks * 32);
    }

    // stage B-half (output cols nh*64..nh*64+63) into padded LDS
    #pragma unroll
    for (int i = 0; i < 8; ++i) {
        int flat = i * 256 + t;            // 16B frag id, 0..2047
        int rw = flat >> 5, fr = flat & 31;
        uint4 v = *((const uint4*)(Wt + (size_t)(nh * 64 + rw) * K2) + fr);
        *(uint4*)(&sB[rw * BROW + fr * 8]) = v;
    }
    __syncthreads();

    floatx4 acc[2][4];
    #pragma unroll
    for (int i = 0; i < 2; ++i)
        #pragma unroll
        for (int j = 0; j < 4; ++j) acc[i][j] = (floatx4){0.f, 0.f, 0.f, 0.f};

    #pragma unroll
    for (int ks = 0; ks < 8; ++ks) {
        #pragma unroll
        for (int nb = 0; nb < 4; ++nb) {
            short8 b = *(const short8*)(&sB[(nb * 16 + l16) * BROW + ks * 32 + q * 8]);
            acc[0][nb] = __builtin_amdgcn_mfma_f32_16x16x32_bf16(a0[ks], b, acc[0][nb], 0, 0, 0);
            acc[1][nb] = __builtin_amdgcn_mfma_f32_16x16x32_bf16(a1[ks], b, acc[1][nb], 0, 0, 0);
        }
    }

    float bv[4], gwv[4];
    #pragma unroll
    for (int nb = 0; nb < 4; ++nb) bv[nb] = bias[nh * 64 + nb * 16 + l16];
    if (gate_w) {
        #pragma unroll
        for (int nb = 0; nb < 4; ++nb) gwv[nb] = gate_w[nh * 64 + nb * 16 + l16];
    }

    // epilogue: relu+bias -> per-wave LDS tile (rows 0..31 x cols 0..63)
    #pragma unroll
    for (int band = 0; band < 2; ++band) {
        #pragma unroll
        for (int r = 0; r < 4; ++r) {
            int lr = band * 16 + q * 4 + r;   // local row 0..31
            float gsum = 0.f;
            #pragma unroll
            for (int nb = 0; nb < 4; ++nb) {
                float v = fmaxf(acc[band][nb][r] + bv[nb], 0.f);
                sOut[wave][lr * OROW + nb * 16 + l16] = f2bf(v);
                if (gate_w) gsum += v * gwv[nb];
            }
            if (gate_w) {
                gsum += __shfl_xor(gsum, 1);
                gsum += __shfl_xor(gsum, 2);
                gsum += __shfl_xor(gsum, 4);
                gsum += __shfl_xor(gsum, 8);
                int m = row0 + lr;
                if (l16 == 0 && m < N_NODES) atomicAdd(&gate[m], gsum);
            }
        }
    }

    // coalesced store-back: lane covers (row r2, 32-short half h2)
    int r2 = lane >> 1, h2 = lane & 1;
    size_t gbase = (size_t)(row0 + r2) * K2 + FEAT + nh * 64 + h2 * 32;
    #pragma unroll
    for (int j = 0; j < 2; ++j) {
        uint4 v0 = *(uint4*)(&sOut[wave][r2 * OROW + h2 * 32 + j * 16]);
        uint4 v1 = *(uint4*)(&sOut[wave][r2 * OROW + h2 * 32 + j * 16 + 8]);
        *(uint4*)(Aout + gbase + j * 16) = v0;
        *(uint4*)(Aout + gbase + j * 16 + 8) = v1;
    }
}

// ---------- pooling + head: one block (256 thr) per graph ----------
// Computes its own segment max (gate is L2-hot, ~98 nodes/graph).
__global__ __launch_bounds__(256) void pool_head(
    const unsigned short* __restrict__ h, const float* __restrict__ gate,
    const int* __restrict__ goffs,
    const float* __restrict__ w1, const float* __restrict__ b1,
    const float* __restrict__ w2, const float* __restrict__ b2,
    float* __restrict__ out) {
    __shared__ float sred[4];
    __shared__ float facc[4][128];
    __shared__ float pv[128], qv[128], lg[N_CLASSES];
    int g = blockIdx.x;
    int s = goffs[g], e = goffs[g + 1];
    int t = threadIdx.x;
    int wave = t >> 6, lane = t & 63;

    if (s < e) {
        // segment max
        float mx = -INFINITY;
        for (int n = s + t; n < e; n += 256) mx = fmaxf(mx, gate[n]);
        #pragma unroll
        for (int off = 32; off; off >>= 1) mx = fmaxf(mx, __shfl_xor(mx, off));
        if (lane == 0) sred[wave] = mx;
        __syncthreads();
        float m = fmaxf(fmaxf(sred[0], sred[1]), fmaxf(sred[2], sred[3]));
        __syncthreads();
        // denominator
        float d = 0.f;
        for (int n = s + t; n < e; n += 256) d += __expf(gate[n] - m);
        #pragma unroll
        for (int off = 32; off; off >>= 1) d += __shfl_xor(d, off);
        if (lane == 0) sred[wave] = d;
        __syncthreads();
        float den = sred[0] + sred[1] + sred[2] + sred[3];
        // weighted feature sum
        float acc0 = 0.f, acc1 = 0.f;
        for (int n = s + wave; n < e; n += 4) {
            float gn = __expf(gate[n] - m);
            unsigned u = *(const unsigned*)(h + (size_t)n * K2 + lane * 2);
            acc0 += gn * bflo(u);
            acc1 += gn * bfhi(u);
        }
        facc[wave][lane * 2]     = acc0;
        facc[wave][lane * 2 + 1] = acc1;
        __syncthreads();
        if (t < 128) pv[t] = (facc[0][t] + facc[1][t] + facc[2][t] + facc[3][t]) / den;
    } else {
        if (t < 128) pv[t] = 0.f;
    }
    __syncthreads();

    if (t < 128) {
        float acc = b1[t];
        #pragma unroll 4
        for (int k = 0; k < 128; ++k) acc += pv[k] * w1[k * FEAT + t];
        qv[t] = fmaxf(acc, 0.f);
    }
    __syncthreads();
    if (t < N_CLASSES) {
        float a = b2[t];
        #pragma unroll 4
        for (int k = 0; k < 128; ++k) a += qv[k] * w2[k * N_CLASSES + t];
        lg[t] = a;
    }
    __syncthreads();
    if (t < N_CLASSES) {
        float m = -INFINITY;
        #pragma unroll
        for (int j = 0; j < N_CLASSES; ++j) m = fmaxf(m, lg[j]);
        float sum = 0.f;
        #pragma unroll
        for (int j = 0; j < N_CLASSES; ++j) sum += __expf(lg[j] - m);
        out[(size_t)g * N_CLASSES + t] = lg[t] - m - __logf(sum);
    }
}

// ---------- launch ----------
static inline size_t align256(size_t x) { return (x + 255) & ~(size_t)255; }

extern "C" void kernel_launch(void* const* d_in, const int* in_sizes, int n_in,
                              void* d_out, int out_size, void* d_ws, size_t ws_size,
                              hipStream_t stream) {
    const float* x        = (const float*)d_in[0];
    const int*   ei       = (const int*)d_in[1];
    const int*   batch    = (const int*)d_in[2];
    const float* conv1_wl = (const float*)d_in[4];
    const float* conv1_wr = (const float*)d_in[5];
    const float* conv1_b  = (const float*)d_in[6];
    const float* convs_wl = (const float*)d_in[7];
    const float* convs_wr = (const float*)d_in[8];
    const float* convs_b  = (const float*)d_in[9];
    const float* gate_w   = (const float*)d_in[10];
    const float* lin1_w   = (const float*)d_in[12];
    const float* lin1_b   = (const float*)d_in[13];
    const float* lin2_w   = (const float*)d_in[14];
    const float* lin2_b   = (const float*)d_in[15];
    float* out = (float*)d_out;

    const int* src = ei;
    const int* dst = ei + N_EDGES;

    char* w = (char*)d_ws;
    size_t off = 0;
    unsigned short* A0   = (unsigned short*)(w + off); off += align256((size_t)N_PAD * K2 * 2);
    unsigned short* A1   = (unsigned short*)(w + off); off += align256((size_t)N_PAD * K2 * 2);
    unsigned short* bkt  = (unsigned short*)(w + off); off += align256((size_t)N_NODES * BCAP * 2);
    unsigned short* wt   = (unsigned short*)(w + off); off += align256((size_t)3 * FEAT * K2 * 2);
    int*   i_goff = (int*)(w + off);   off += align256((size_t)(N_GRAPHS + 1) * 4);
    // zero region: cnt + gate contiguous
    char* zbase = w + off;
    int*   i_cnt  = (int*)(w + off);   off += align256((size_t)N_NODES * 4);
    float* f_gate = (float*)(w + off); off += align256((size_t)N_NODES * 4);
    size_t zbytes = (size_t)((w + off) - zbase);

    hipMemsetAsync(zbase, 0, zbytes, stream);

    fill_bucket<<<12500, 256, 0, stream>>>(src, dst, i_cnt, bkt);
    setup_kernel<<<6250 + 384 + 3, 256, 0, stream>>>(
        x, A0, conv1_wl, conv1_wr, convs_wl, convs_wr, wt, batch, i_goff);

    const int AB = (N_NODES + 3) / 4;   // 12500
    const int GB = (N_PAD / 128) * 2;   // 782: 391 M-tiles x 2 N-halves

    // ping-pong: A0 -> A1 -> A0 -> A1
    aggregate_bf16<<<AB, 256, 0, stream>>>(A0 + FEAT, i_cnt, bkt, A0);
    gemm_mfma<<<GB, 256, 0, stream>>>(A0, A1, wt, conv1_b, nullptr, nullptr);
    aggregate_bf16<<<AB, 256, 0, stream>>>(A1 + FEAT, i_cnt, bkt, A1);
    gemm_mfma<<<GB, 256, 0, stream>>>(A1, A0, wt + FEAT * K2, convs_b, nullptr, nullptr);
    aggregate_bf16<<<AB, 256, 0, stream>>>(A0 + FEAT, i_cnt, bkt, A0);
    gemm_mfma<<<GB, 256, 0, stream>>>(A0, A1, wt + 2 * FEAT * K2, convs_b + FEAT,
                                      gate_w, f_gate);

    pool_head<<<N_GRAPHS, 256, 0, stream>>>(A1 + FEAT, f_gate, i_goff,
                                            lin1_w, lin1_b, lin2_w, lin2_b, out);
}